// Round 18
// baseline (94.148 us; speedup 1.0000x reference)
//
#include <hip/hip_runtime.h>
#include <math.h>

typedef float f32x4 __attribute__((ext_vector_type(4)));
typedef short s16x8 __attribute__((ext_vector_type(8)));
typedef unsigned u32x4 __attribute__((ext_vector_type(4)));

#define N_NODES 2048
#define KEDGE 32
#define HDIM 128
#define SB() __builtin_amdgcn_sched_barrier(0)

__device__ __forceinline__ short f2bf(float f){
  unsigned u = __builtin_bit_cast(unsigned, f);
  u += 0x7fffu + ((u >> 16) & 1u);
  return (short)(u >> 16);
}
__device__ __forceinline__ float bf2f(short s){
  unsigned u = ((unsigned)(unsigned short)s) << 16;
  return __builtin_bit_cast(float, u);
}
__device__ __forceinline__ unsigned cvt_pk_bf16(float a, float b){
  unsigned r;
  asm("v_cvt_pk_bf16_f32 %0, %1, %2" : "=v"(r) : "v"(a), "v"(b));
  return r;
}
// tanh-form GELU via exp2+rcp: max abs error vs exact ~5e-4
__device__ __forceinline__ float fast_gelu(float x){
  float t = x * (-2.3022078f - 0.1029527f * x * x);
  float e = __builtin_amdgcn_exp2f(t);
  return x * __builtin_amdgcn_rcpf(1.0f + e);
}
__device__ __forceinline__ void gld16(const void* g, void* l){
  __builtin_amdgcn_global_load_lds(
      (const __attribute__((address_space(1))) void*)g,
      (__attribute__((address_space(3))) void*)l, 16, 0, 0);
}
__device__ __forceinline__ f32x4 mfma16(s16x8 a, s16x8 b, f32x4 c){
  return __builtin_amdgcn_mfma_f32_16x16x32_bf16(a, b, c, 0, 0, 0);
}

// ---- prep1: pack W1/W2 fp32 -> bf16 MFMA B-frag order; init idx flag ----
// elem((ks,ct,lane,j)) = W[ks*32 + (lane>>4)*8 + j][ct*16 + (lane&15)]
__global__ void prep1(const float* __restrict__ W1, const float* __restrict__ W2,
                      short* __restrict__ W1f, short* __restrict__ W2f,
                      unsigned* __restrict__ flag){
  if (blockIdx.x == 320){
    if (threadIdx.x == 0) *flag = 0u;
    return;
  }
  int t = blockIdx.x * 256 + threadIdx.x;
  if (t < 65536){
    int ks = t >> 12, r = t & 4095;
    int ct = r >> 9;  r &= 511;
    int lane = r >> 3, j = r & 7;
    int k = ks*32 + (lane>>4)*8 + j;
    int n = ct*16 + (lane&15);
    W1f[t] = f2bf(W1[k*128 + n]);
  } else if (t < 81920){
    int t2 = t - 65536;
    int ks = t2 >> 12, r = t2 & 4095;
    int ct = r >> 9;  r &= 511;
    int lane = r >> 3, j = r & 7;
    int k = ks*32 + (lane>>4)*8 + j;
    int n = ct*16 + (lane&15);
    W2f[t2] = f2bf(W2[k*128 + n]);
  }
}

// ---- prep2: Zb (bf16 rows) + UHb ({U',hV} bf16 pairs) + E_idx detect ----
//   Zb[m][:]              = bf16( hS(m)@W1c + hV(m)@W1d )
//   UHb[m][l15*8 + ct]    = u32( bf16(U'[ct*16+l15]) | bf16(hV[ct*16+l15])<<16 )
__global__ __launch_bounds__(256)
void prep2(const float* __restrict__ hS, const float* __restrict__ hV,
           const float* __restrict__ b1, const short* __restrict__ W1f,
           short* __restrict__ Zb, unsigned* __restrict__ UHb,
           const unsigned* __restrict__ Ei_u, unsigned* __restrict__ flag){
  if (blockIdx.x >= 128){
    int t = ((int)blockIdx.x - 128)*256 + threadIdx.x;   // t < 131072
    unsigned v = Ei_u[2*t + 1];
    unsigned long long m = __ballot(v != 0u);
    if ((threadIdx.x & 63) == 0 && m) atomicOr(flag, 1u);
    return;
  }
  const int tid = threadIdx.x;
  const int w = tid >> 6, lane = tid & 63, l15 = lane & 15, lg = lane >> 4;
  const int nb = ((int)blockIdx.x*4 + w)*16;

  f32x4 accz[8], accu[8];
  #pragma unroll
  for (int ct = 0; ct < 8; ++ct){ accz[ct] = (f32x4){0,0,0,0}; accu[ct] = (f32x4){0,0,0,0}; }

  #pragma unroll
  for (int ks = 0; ks < 4; ++ks){
    const float* p = hS + (long)(nb + l15)*128 + ks*32 + lg*8;
    float4 x = *(const float4*)p, y = *(const float4*)(p + 4);
    u32x4 pk;
    pk[0] = cvt_pk_bf16(x.x, x.y); pk[1] = cvt_pk_bf16(x.z, x.w);
    pk[2] = cvt_pk_bf16(y.x, y.y); pk[3] = cvt_pk_bf16(y.z, y.w);
    s16x8 a = __builtin_bit_cast(s16x8, pk);
    #pragma unroll
    for (int ct = 0; ct < 8; ++ct){
      s16x8 bf = *(const s16x8*)(W1f + (8+ks)*4096 + ct*512 + lane*8);
      accz[ct] = mfma16(a, bf, accz[ct]);
    }
  }
  #pragma unroll
  for (int ks = 0; ks < 4; ++ks){
    const float* p = hV + (long)(nb + l15)*128 + ks*32 + lg*8;
    float4 x = *(const float4*)p, y = *(const float4*)(p + 4);
    u32x4 pk;
    pk[0] = cvt_pk_bf16(x.x, x.y); pk[1] = cvt_pk_bf16(x.z, x.w);
    pk[2] = cvt_pk_bf16(y.x, y.y); pk[3] = cvt_pk_bf16(y.z, y.w);
    s16x8 a = __builtin_bit_cast(s16x8, pk);
    #pragma unroll
    for (int ct = 0; ct < 8; ++ct){
      s16x8 bfd = *(const s16x8*)(W1f + (12+ks)*4096 + ct*512 + lane*8);
      accz[ct] = mfma16(a, bfd, accz[ct]);
      s16x8 bfa = *(const s16x8*)(W1f + (0+ks)*4096 + ct*512 + lane*8);
      accu[ct] = mfma16(a, bfa, accu[ct]);
    }
  }

  float b1v[8];
  #pragma unroll
  for (int ct = 0; ct < 8; ++ct) b1v[ct] = b1[ct*16 + l15];

  #pragma unroll
  for (int ct = 0; ct < 8; ++ct)
    #pragma unroll
    for (int i = 0; i < 4; ++i){
      const long row = nb + lg*4 + i;
      Zb[row*128 + ct*16 + l15] = f2bf(accz[ct][i]);
      unsigned u16 = (unsigned)(unsigned short)f2bf(accu[ct][i] + b1v[ct]);
      unsigned h16 = (unsigned)(unsigned short)f2bf(hV[row*128 + ct*16 + l15]);
      UHb[row*128 + l15*8 + ct] = u16 | (h16 << 16);
    }
}

// ---- fused: r17 verified core (passed, 176 VGPR no-spill), re-gridded for
// backfill: 1024 blocks x 2 nodes/wave (T=4). With 2 resident blocks/CU and
// 1024 total, the scheduler backfills finished slots (512 had none), and the
// per-block cold-start amortizes off the critical path. FIFO per iter
// unchanged: A(4)|S(8 gld16)|Z(4); split waits vmcnt(20) [S(t) done, GEMM1
// starts] then vmcnt(16) [Z(t-1) done, inject+gelu]; last iter vmcnt(0).
__global__ __launch_bounds__(256, 1)
void fusedF(const float* __restrict__ hE, const int* __restrict__ Eidx,
            const float* __restrict__ mask, const short* __restrict__ W1f,
            const short* __restrict__ W2f, const short* __restrict__ Zb,
            const unsigned* __restrict__ UHb, const unsigned* __restrict__ idx_flag,
            const float* __restrict__ W2b, const float* __restrict__ lng,
            const float* __restrict__ lnb, float* __restrict__ out)
{
  // [0,65536): 4 waves x (2 x 8KB hE dbuf); [65536,67584): v-park (4 x 512B)
  __shared__ __align__(16) char smem[67584];

  const int tid  = threadIdx.x;
  const int w    = tid >> 6;
  const int lane = tid & 63;
  const int l15  = lane & 15;
  const int lg   = lane >> 4;

  const int bid  = (int)blockIdx.x;
  const int bswz = (bid & 7)*128 + (bid >> 3);       // XCD swizzle (1024%8==0)
  const int n0 = (bswz * 4 + w) * 2;                 // 2 nodes/wave: 8192 total
  const long zrow0 = (long)(n0 >> 11) * N_NODES;     // batch base (r8 lesson)
  char* mybuf  = smem + w*16384;
  short* vpark = (short*)(smem + 65536 + w*512);     // 2 nodes x 128 bf16

  // staging source swizzle (m173, r12/r14-verified):
  // row = 2q+rr; LDS[row*512+col] = hErow[col ^ ((row&7)<<4)]
  const int rr = lane >> 5;
  const unsigned t0 = (unsigned)((rr << 9) | (((lane & 31) << 4) ^ (rr << 4)));

  // ---- W1b B-frags into registers (128 VGPR) ----
  s16x8 wf[4][8];
  #pragma unroll
  for (int ks = 0; ks < 4; ++ks)
    #pragma unroll
    for (int ct = 0; ct < 8; ++ct)
      wf[ks][ct] = *(const s16x8*)(W1f + (4+ks)*4096 + ct*512 + lane*8);
  SB();

  // identity B-frags for Z injection (exact in bf16)
  s16x8 ifr[2];
  #pragma unroll
  for (int c2 = 0; c2 < 2; ++c2){
    const int active = ((lg >> 1) == c2);
    const int j = l15 - 8*(lg & 1);
    s16x8 f;
    #pragma unroll
    for (int e = 0; e < 8; ++e)
      f[e] = (active && j == e) ? (short)0x3F80 : (short)0;
    ifr[c2] = f;
  }

  const int is64 = (*idx_flag == 0u) ? 1 : 0;

  // ---- prologue: A(0), S(0)=stage(it0), Z(0)=zb(it0) ----
  int e0, eZ;
  {
    const int ea = n0*32 + l15;                      // it0: node n0, half 0
    const int eb = n0*32 + 16 + l15;                 // it1: node n0, half 1
    e0 = Eidx[ea << is64];
    eZ = Eidx[eb << is64];
  }
  float maskC = mask[n0*32 + l15];
  s16x8 uhC[2];
  uhC[0] = *(const s16x8*)((const short*)UHb + (long)n0*256 + l15*16);
  uhC[1] = *(const s16x8*)((const short*)UHb + (long)n0*256 + l15*16 + 8);
  SB();
  #pragma unroll
  for (int q = 0; q < 8; ++q){
    const unsigned off = (unsigned)(q*1024) | (t0 ^ (unsigned)((2*q & 6) << 4));
    gld16((const char*)hE + (size_t)n0*16384 + off, mybuf + q*1024);
  }
  SB();
  s16x8 zbC[4];
  #pragma unroll
  for (int ks = 0; ks < 4; ++ks)
    zbC[ks] = *(const s16x8*)(Zb + (zrow0 + e0)*128 + ks*32 + lg*8);
  SB();
  asm volatile("s_waitcnt vmcnt(0)" ::: "memory");   // cold start (once)
  SB();

  float vacc[8];
  #pragma unroll
  for (int ct = 0; ct < 8; ++ct) vacc[ct] = 0.f;

  #pragma unroll
  for (int t = 0; t < 4; ++t){
    const int tn = t + 1;
    float maskN = 0.f; s16x8 uhN0{}, uhN1{}; int eN = 0;
    s16x8 zbN0{}, zbN1{}, zbN2{}, zbN3{};
    if (t < 3){
      const int nn_n = n0 + (tn >> 1);
      // ---- A: state for t+1 (mask, uh) and eidx for t+2 : 4 VMEM ----
      SB();
      maskN = mask[nn_n*32 + (tn&1)*16 + l15];
      uhN0 = *(const s16x8*)((const short*)UHb + (long)nn_n*256 + l15*16);
      uhN1 = *(const s16x8*)((const short*)UHb + (long)nn_n*256 + l15*16 + 8);
      {
        const int t2 = t + 2;
        const int nz = (t2 <= 3) ? (n0 + (t2>>1)) : n0;   // compile-time select
        const int hz = (t2 <= 3) ? (t2&1) : 0;
        eN = Eidx[(nz*32 + hz*16 + l15) << is64];
      }
      SB();
      // ---- S: stage(t+1) -> slot (t+1)&1 : exactly 8 gld16 ----
      {
        const size_t eb = (size_t)nn_n*16384 + (size_t)(tn&1)*8192;
        char* sbuf = mybuf + (tn&1)*8192;
        #pragma unroll
        for (int q = 0; q < 8; ++q){
          const unsigned off = (unsigned)(q*1024) | (t0 ^ (unsigned)((2*q & 6) << 4));
          gld16((const char*)hE + eb + off, sbuf + q*1024);
        }
      }
      SB();
      // ---- Z: zb(t+1) : 4 gathered b128 (Zb is L2-resident) ----
      zbN0 = *(const s16x8*)(Zb + (zrow0 + eZ)*128 + 0*32 + lg*8);
      zbN1 = *(const s16x8*)(Zb + (zrow0 + eZ)*128 + 1*32 + lg*8);
      zbN2 = *(const s16x8*)(Zb + (zrow0 + eZ)*128 + 2*32 + lg*8);
      zbN3 = *(const s16x8*)(Zb + (zrow0 + eZ)*128 + 3*32 + lg*8);
      SB();
      // ---- SPLIT WAIT 1: S(t) complete (younger = Z(t-1)4 + A/S/Z(t+1)16
      // = 20). GEMM1 starts; Z/A latency hides under the 32-MFMA burst. ----
      asm volatile("s_waitcnt vmcnt(20)" ::: "memory");
      SB();
    } else {
      asm volatile("s_waitcnt vmcnt(0)" ::: "memory");   // last iter: drain
      SB();
    }

    // ---- compute(t) part 1: GEMM1 (LDS hE x reg W1), 32 MFMA ----
    f32x4 acc1[8];
    #pragma unroll
    for (int ct = 0; ct < 8; ++ct) acc1[ct] = (f32x4){0,0,0,0};

    s16x8 afr[4];
    const char* cbuf = mybuf + (t&1)*8192;
    const int sw = (l15 & 7) << 4;
    const int rowb = l15 * 512;
    #pragma unroll
    for (int ks = 0; ks < 4; ++ks){
      const int c0 = ks*128 + lg*32;
      float4 ex = *(const float4*)(cbuf + rowb + (c0 ^ sw));
      float4 ey = *(const float4*)(cbuf + rowb + ((c0 + 16) ^ sw));
      u32x4 pk;
      pk[0] = cvt_pk_bf16(ex.x, ex.y); pk[1] = cvt_pk_bf16(ex.z, ex.w);
      pk[2] = cvt_pk_bf16(ey.x, ey.y); pk[3] = cvt_pk_bf16(ey.z, ey.w);
      afr[ks] = __builtin_bit_cast(s16x8, pk);
      #pragma unroll
      for (int ct = 0; ct < 8; ++ct)
        acc1[ct] = mfma16(afr[ks], wf[ks][ct], acc1[ct]);
    }

    // ---- SPLIT WAIT 2: Z(t-1)=zbC + A(t-1)=uh/mask complete
    // (younger = A/S/Z(t+1) = 16). ----
    if (t < 3){
      asm volatile("s_waitcnt vmcnt(16)" ::: "memory");
      SB();
    }

    // ---- compute(t) part 2: Z inject (8 MFMA) + U' + mask + gelu ----
    #pragma unroll
    for (int ks = 0; ks < 4; ++ks)
      #pragma unroll
      for (int c2 = 0; c2 < 2; ++c2)
        acc1[ks*2 + c2] = mfma16(zbC[ks], ifr[c2], acc1[ks*2 + c2]);

    float uv[8];
    #pragma unroll
    for (int ct = 0; ct < 4; ++ct){ uv[ct] = bf2f(uhC[0][2*ct]); uv[4+ct] = bf2f(uhC[1][2*ct]); }
    float mi[4];
    #pragma unroll
    for (int i = 0; i < 4; ++i) mi[i] = __shfl(maskC, lg*4 + i, 64);
    #pragma unroll
    for (int ct = 0; ct < 8; ++ct)
      #pragma unroll
      for (int i = 0; i < 4; ++i)
        vacc[ct] += fast_gelu(uv[ct] + mi[i]*acc1[ct][i]);

    // ---- odd iter: node complete -> reduce 32 edges, park v in LDS ----
    if (t & 1){
      short* vl = vpark + (t >> 1)*128;              // compile-time offset
      #pragma unroll
      for (int ct = 0; ct < 8; ++ct){
        float s = vacc[ct];
        s += __shfl_xor(s, 16, 64);
        s += __shfl_xor(s, 32, 64);
        vacc[ct] = 0.f;
        if (ct == lg*2 || ct == lg*2 + 1)
          vl[ct*16 + l15] = f2bf(s);
      }
    }

    // rotate
    if (t < 3){
      maskC = maskN; uhC[0] = uhN0; uhC[1] = uhN1; eZ = eN;
      zbC[0] = zbN0; zbC[1] = zbN1; zbC[2] = zbN2; zbC[3] = zbN3;
    }
  }

  // ---- post-loop epilogue: GEMM2 + LayerNorm + store, per node ----
  asm volatile("s_waitcnt lgkmcnt(0)" ::: "memory");  // v-park visible (r2/r6)
  SB();

  float w2b8[8], lngv[2], lnbv[2];
  #pragma unroll
  for (int ct = 0; ct < 8; ++ct) w2b8[ct] = W2b[ct*16 + l15];
  #pragma unroll
  for (int q = 0; q < 2; ++q){
    const int c = (lg*2 + q)*16 + l15;
    lngv[q] = lng[c]; lnbv[q] = lnb[c];
  }

  #pragma unroll
  for (int nd = 0; nd < 2; ++nd){
    const short* vl = vpark + nd*128;
    f32x4 acc2[8];
    #pragma unroll
    for (int ct = 0; ct < 8; ++ct) acc2[ct] = (f32x4){0,0,0,0};
    #pragma unroll
    for (int ks2 = 0; ks2 < 4; ++ks2){
      s16x8 av = *(const s16x8*)(vl + ks2*32 + lg*8);
      const short* wb2 = W2f + ks2*4096 + lane*8;    // global, L1/L2-hot
      #pragma unroll
      for (int ct = 0; ct < 8; ++ct){
        s16x8 bf = *(const s16x8*)(wb2 + ct*512);
        acc2[ct] = mfma16(av, bf, acc2[ct]);
      }
    }

    s16x8 uh0 = *(const s16x8*)((const short*)UHb + (long)(n0+nd)*256 + l15*16);
    s16x8 uh1 = *(const s16x8*)((const short*)UHb + (long)(n0+nd)*256 + l15*16 + 8);
    float hv[8];
    #pragma unroll
    for (int ct = 0; ct < 4; ++ct){ hv[ct] = bf2f(uh0[2*ct+1]); hv[4+ct] = bf2f(uh1[2*ct+1]); }

    float res[8], vs = 0.f, vq = 0.f;
    #pragma unroll
    for (int ct = 0; ct < 8; ++ct){
      float dh  = (acc2[ct][0] + 32.0f * w2b8[ct]) * (1.0f/30.0f);
      float val = hv[ct] + dh;
      res[ct] = val;
      vs += val; vq += val*val;
    }
    vs += __shfl_xor(vs, 1, 64);  vs += __shfl_xor(vs, 2, 64);
    vs += __shfl_xor(vs, 4, 64);  vs += __shfl_xor(vs, 8, 64);
    vq += __shfl_xor(vq, 1, 64);  vq += __shfl_xor(vq, 2, 64);
    vq += __shfl_xor(vq, 4, 64);  vq += __shfl_xor(vq, 8, 64);
    const float mu  = vs * (1.0f/128.0f);
    const float var = vq * (1.0f/128.0f) - mu*mu;
    const float rs  = rsqrtf(var + 1e-5f);

    const long nodeoff = (long)(n0 + nd) * HDIM;
    #pragma unroll
    for (int q = 0; q < 2; ++q){
      const int ct = lg*2 + q;
      out[nodeoff + ct*16 + l15] = (res[ct] - mu) * rs * lngv[q] + lnbv[q];
    }
  }
}

extern "C" void kernel_launch(void* const* d_in, const int* in_sizes, int n_in,
                              void* d_out, int out_size, void* d_ws, size_t ws_size,
                              hipStream_t stream) {
  const float* hS  = (const float*)d_in[0];
  const float* hV  = (const float*)d_in[1];
  const float* hE  = (const float*)d_in[2];
  const int*   Ei  = (const int*)d_in[3];
  const float* mk  = (const float*)d_in[4];
  const float* W1w = (const float*)d_in[5];
  const float* W1b = (const float*)d_in[6];
  const float* W2w = (const float*)d_in[7];
  const float* W2b = (const float*)d_in[8];
  const float* lng = (const float*)d_in[9];
  const float* lnb = (const float*)d_in[10];

  short* W1f = (short*)d_ws;                           // 128 KB @0
  short* W2f = W1f + 65536;                            // 32 KB @131072
  unsigned* flag = (unsigned*)((char*)d_ws + 163840);
  short* Zb = (short*)((char*)d_ws + 164096);          // 2 MB
  unsigned* UHb = (unsigned*)((char*)d_ws + 2261248);  // 4 MB
  // ~6.5 MB used; ws is >=512 MB (r14 fillBuffer evidence)

  prep1<<<321, 256, 0, stream>>>(W1w, W2w, W1f, W2f, flag);
  prep2<<<640, 256, 0, stream>>>(hS, hV, W1b, W1f, Zb, UHb, (const unsigned*)Ei, flag);
  fusedF<<<1024, 256, 0, stream>>>(hE, Ei, mk, W1f, W2f, Zb, UHb, flag,
                                   W2b, lng, lnb, (float*)d_out);
}

// Round 19
// 88.529 us; speedup vs baseline: 1.0635x; 1.0635x over previous
//
#include <hip/hip_runtime.h>
#include <math.h>

typedef float f32x4 __attribute__((ext_vector_type(4)));
typedef short s16x8 __attribute__((ext_vector_type(8)));
typedef unsigned u32x4 __attribute__((ext_vector_type(4)));

#define N_NODES 2048
#define KEDGE 32
#define HDIM 128
#define SB() __builtin_amdgcn_sched_barrier(0)

__device__ __forceinline__ short f2bf(float f){
  unsigned u = __builtin_bit_cast(unsigned, f);
  u += 0x7fffu + ((u >> 16) & 1u);
  return (short)(u >> 16);
}
__device__ __forceinline__ float bf2f(short s){
  unsigned u = ((unsigned)(unsigned short)s) << 16;
  return __builtin_bit_cast(float, u);
}
__device__ __forceinline__ unsigned cvt_pk_bf16(float a, float b){
  unsigned r;
  asm("v_cvt_pk_bf16_f32 %0, %1, %2" : "=v"(r) : "v"(a), "v"(b));
  return r;
}
// tanh-form GELU via exp2+rcp: max abs error vs exact ~5e-4
__device__ __forceinline__ float fast_gelu(float x){
  float t = x * (-2.3022078f - 0.1029527f * x * x);
  float e = __builtin_amdgcn_exp2f(t);
  return x * __builtin_amdgcn_rcpf(1.0f + e);
}
__device__ __forceinline__ void gld16(const void* g, void* l){
  __builtin_amdgcn_global_load_lds(
      (const __attribute__((address_space(1))) void*)g,
      (__attribute__((address_space(3))) void*)l, 16, 0, 0);
}
__device__ __forceinline__ f32x4 mfma16(s16x8 a, s16x8 b, f32x4 c){
  return __builtin_amdgcn_mfma_f32_16x16x32_bf16(a, b, c, 0, 0, 0);
}

// ---- prep1: pack W1/W2 fp32 -> bf16 MFMA B-frag order; init idx flag ----
// elem((ks,ct,lane,j)) = W[ks*32 + (lane>>4)*8 + j][ct*16 + (lane&15)]
__global__ void prep1(const float* __restrict__ W1, const float* __restrict__ W2,
                      short* __restrict__ W1f, short* __restrict__ W2f,
                      unsigned* __restrict__ flag){
  if (blockIdx.x == 320){
    if (threadIdx.x == 0) *flag = 0u;
    return;
  }
  int t = blockIdx.x * 256 + threadIdx.x;
  if (t < 65536){
    int ks = t >> 12, r = t & 4095;
    int ct = r >> 9;  r &= 511;
    int lane = r >> 3, j = r & 7;
    int k = ks*32 + (lane>>4)*8 + j;
    int n = ct*16 + (lane&15);
    W1f[t] = f2bf(W1[k*128 + n]);
  } else if (t < 81920){
    int t2 = t - 65536;
    int ks = t2 >> 12, r = t2 & 4095;
    int ct = r >> 9;  r &= 511;
    int lane = r >> 3, j = r & 7;
    int k = ks*32 + (lane>>4)*8 + j;
    int n = ct*16 + (lane&15);
    W2f[t2] = f2bf(W2[k*128 + n]);
  }
}

// ---- prep2: Zb (bf16 rows) + UHb ({U',hV} bf16 pairs) + E_idx detect ----
//   Zb[m][:]              = bf16( hS(m)@W1c + hV(m)@W1d )
//   UHb[m][l15*8 + ct]    = u32( bf16(U'[ct*16+l15]) | bf16(hV[ct*16+l15])<<16 )
__global__ __launch_bounds__(256)
void prep2(const float* __restrict__ hS, const float* __restrict__ hV,
           const float* __restrict__ b1, const short* __restrict__ W1f,
           short* __restrict__ Zb, unsigned* __restrict__ UHb,
           const unsigned* __restrict__ Ei_u, unsigned* __restrict__ flag){
  if (blockIdx.x >= 128){
    int t = ((int)blockIdx.x - 128)*256 + threadIdx.x;   // t < 131072
    unsigned v = Ei_u[2*t + 1];
    unsigned long long m = __ballot(v != 0u);
    if ((threadIdx.x & 63) == 0 && m) atomicOr(flag, 1u);
    return;
  }
  const int tid = threadIdx.x;
  const int w = tid >> 6, lane = tid & 63, l15 = lane & 15, lg = lane >> 4;
  const int nb = ((int)blockIdx.x*4 + w)*16;

  f32x4 accz[8], accu[8];
  #pragma unroll
  for (int ct = 0; ct < 8; ++ct){ accz[ct] = (f32x4){0,0,0,0}; accu[ct] = (f32x4){0,0,0,0}; }

  #pragma unroll
  for (int ks = 0; ks < 4; ++ks){
    const float* p = hS + (long)(nb + l15)*128 + ks*32 + lg*8;
    float4 x = *(const float4*)p, y = *(const float4*)(p + 4);
    u32x4 pk;
    pk[0] = cvt_pk_bf16(x.x, x.y); pk[1] = cvt_pk_bf16(x.z, x.w);
    pk[2] = cvt_pk_bf16(y.x, y.y); pk[3] = cvt_pk_bf16(y.z, y.w);
    s16x8 a = __builtin_bit_cast(s16x8, pk);
    #pragma unroll
    for (int ct = 0; ct < 8; ++ct){
      s16x8 bf = *(const s16x8*)(W1f + (8+ks)*4096 + ct*512 + lane*8);
      accz[ct] = mfma16(a, bf, accz[ct]);
    }
  }
  #pragma unroll
  for (int ks = 0; ks < 4; ++ks){
    const float* p = hV + (long)(nb + l15)*128 + ks*32 + lg*8;
    float4 x = *(const float4*)p, y = *(const float4*)(p + 4);
    u32x4 pk;
    pk[0] = cvt_pk_bf16(x.x, x.y); pk[1] = cvt_pk_bf16(x.z, x.w);
    pk[2] = cvt_pk_bf16(y.x, y.y); pk[3] = cvt_pk_bf16(y.z, y.w);
    s16x8 a = __builtin_bit_cast(s16x8, pk);
    #pragma unroll
    for (int ct = 0; ct < 8; ++ct){
      s16x8 bfd = *(const s16x8*)(W1f + (12+ks)*4096 + ct*512 + lane*8);
      accz[ct] = mfma16(a, bfd, accz[ct]);
      s16x8 bfa = *(const s16x8*)(W1f + (0+ks)*4096 + ct*512 + lane*8);
      accu[ct] = mfma16(a, bfa, accu[ct]);
    }
  }

  float b1v[8];
  #pragma unroll
  for (int ct = 0; ct < 8; ++ct) b1v[ct] = b1[ct*16 + l15];

  #pragma unroll
  for (int ct = 0; ct < 8; ++ct)
    #pragma unroll
    for (int i = 0; i < 4; ++i){
      const long row = nb + lg*4 + i;
      Zb[row*128 + ct*16 + l15] = f2bf(accz[ct][i]);
      unsigned u16 = (unsigned)(unsigned short)f2bf(accu[ct][i] + b1v[ct]);
      unsigned h16 = (unsigned)(unsigned short)f2bf(hV[row*128 + ct*16 + l15]);
      UHb[row*128 + l15*8 + ct] = u16 | (h16 << 16);
    }
}

// ---- fused: r17 verified optimum. GEMM1+gelu (pipelined loop) then
// GEMM2+LN (post-loop epilogue). 256 thr (4 waves), grid 512,
// __launch_bounds__(256,1): the only spelling that allocates >128 VGPR
// without spill (176 VGPR, WRITE_SIZE=out-only). LDS 68KB -> 2 blocks/CU
// -> 2 waves/SIMD TLP. W1 B-frags in registers. Split waits: vmcnt(20)
// [S(t) done -> GEMM1] then vmcnt(16) [Z(t-1) done -> inject+gelu].
__global__ __launch_bounds__(256, 1)
void fusedF(const float* __restrict__ hE, const int* __restrict__ Eidx,
            const float* __restrict__ mask, const short* __restrict__ W1f,
            const short* __restrict__ W2f, const short* __restrict__ Zb,
            const unsigned* __restrict__ UHb, const unsigned* __restrict__ idx_flag,
            const float* __restrict__ W2b, const float* __restrict__ lng,
            const float* __restrict__ lnb, float* __restrict__ out)
{
  // [0,65536): 4 waves x (2 x 8KB hE dbuf); [65536,69632): v-park (4 x 1KB)
  __shared__ __align__(16) char smem[69632];

  const int tid  = threadIdx.x;
  const int w    = tid >> 6;
  const int lane = tid & 63;
  const int l15  = lane & 15;
  const int lg   = lane >> 4;

  const int bid  = (int)blockIdx.x;
  const int bswz = (bid & 7)*64 + (bid >> 3);        // XCD swizzle (512%8==0)
  const int n0 = (bswz * 4 + w) * 4;                 // 4 nodes/wave: 8192 total
  const long zrow0 = (long)(n0 >> 11) * N_NODES;     // batch base (r8 lesson)
  char* mybuf  = smem + w*16384;
  short* vpark = (short*)(smem + 65536 + w*1024);    // 4 nodes x 128 bf16

  // staging source swizzle (m173, r12/r14-verified):
  // row = 2q+rr; LDS[row*512+col] = hErow[col ^ ((row&7)<<4)]
  const int rr = lane >> 5;
  const unsigned t0 = (unsigned)((rr << 9) | (((lane & 31) << 4) ^ (rr << 4)));

  // ---- W1b B-frags into registers (128 VGPR) ----
  s16x8 wf[4][8];
  #pragma unroll
  for (int ks = 0; ks < 4; ++ks)
    #pragma unroll
    for (int ct = 0; ct < 8; ++ct)
      wf[ks][ct] = *(const s16x8*)(W1f + (4+ks)*4096 + ct*512 + lane*8);
  SB();

  // identity B-frags for Z injection (exact in bf16)
  s16x8 ifr[2];
  #pragma unroll
  for (int c2 = 0; c2 < 2; ++c2){
    const int active = ((lg >> 1) == c2);
    const int j = l15 - 8*(lg & 1);
    s16x8 f;
    #pragma unroll
    for (int e = 0; e < 8; ++e)
      f[e] = (active && j == e) ? (short)0x3F80 : (short)0;
    ifr[c2] = f;
  }

  const int is64 = (*idx_flag == 0u) ? 1 : 0;

  // ---- prologue: A(0), S(0)=stage(it0), Z(0)=zb(it0) ----
  int e0, eZ;
  {
    const int ea = n0*32 + l15;                      // it0: node n0, half 0
    const int eb = n0*32 + 16 + l15;                 // it1: node n0, half 1
    e0 = Eidx[ea << is64];
    eZ = Eidx[eb << is64];
  }
  float maskC = mask[n0*32 + l15];
  s16x8 uhC[2];
  uhC[0] = *(const s16x8*)((const short*)UHb + (long)n0*256 + l15*16);
  uhC[1] = *(const s16x8*)((const short*)UHb + (long)n0*256 + l15*16 + 8);
  SB();
  #pragma unroll
  for (int q = 0; q < 8; ++q){
    const unsigned off = (unsigned)(q*1024) | (t0 ^ (unsigned)((2*q & 6) << 4));
    gld16((const char*)hE + (size_t)n0*16384 + off, mybuf + q*1024);
  }
  SB();
  s16x8 zbC[4];
  #pragma unroll
  for (int ks = 0; ks < 4; ++ks)
    zbC[ks] = *(const s16x8*)(Zb + (zrow0 + e0)*128 + ks*32 + lg*8);
  SB();
  asm volatile("s_waitcnt vmcnt(0)" ::: "memory");   // cold start (once)
  SB();

  float vacc[8];
  #pragma unroll
  for (int ct = 0; ct < 8; ++ct) vacc[ct] = 0.f;

  #pragma unroll
  for (int t = 0; t < 8; ++t){
    const int tn = t + 1;
    float maskN = 0.f; s16x8 uhN0{}, uhN1{}; int eN = 0;
    s16x8 zbN0{}, zbN1{}, zbN2{}, zbN3{};
    if (t < 7){
      const int nn_n = n0 + (tn >> 1);
      // ---- A: state for t+1 (mask, uh) and eidx for t+2 : 4 VMEM ----
      SB();
      maskN = mask[nn_n*32 + (tn&1)*16 + l15];
      uhN0 = *(const s16x8*)((const short*)UHb + (long)nn_n*256 + l15*16);
      uhN1 = *(const s16x8*)((const short*)UHb + (long)nn_n*256 + l15*16 + 8);
      {
        const int t2 = t + 2;
        const int nz = (t2 <= 7) ? (n0 + (t2>>1)) : n0;   // compile-time select
        const int hz = (t2 <= 7) ? (t2&1) : 0;
        eN = Eidx[(nz*32 + hz*16 + l15) << is64];
      }
      SB();
      // ---- S: stage(t+1) -> slot (t+1)&1 : exactly 8 gld16 ----
      {
        const size_t eb = (size_t)nn_n*16384 + (size_t)(tn&1)*8192;
        char* sbuf = mybuf + (tn&1)*8192;
        #pragma unroll
        for (int q = 0; q < 8; ++q){
          const unsigned off = (unsigned)(q*1024) | (t0 ^ (unsigned)((2*q & 6) << 4));
          gld16((const char*)hE + eb + off, sbuf + q*1024);
        }
      }
      SB();
      // ---- Z: zb(t+1) : 4 gathered b128 (Zb is L2-resident) ----
      zbN0 = *(const s16x8*)(Zb + (zrow0 + eZ)*128 + 0*32 + lg*8);
      zbN1 = *(const s16x8*)(Zb + (zrow0 + eZ)*128 + 1*32 + lg*8);
      zbN2 = *(const s16x8*)(Zb + (zrow0 + eZ)*128 + 2*32 + lg*8);
      zbN3 = *(const s16x8*)(Zb + (zrow0 + eZ)*128 + 3*32 + lg*8);
      SB();
      // ---- SPLIT WAIT 1: S(t) complete (staged at iter t-1's S-phase;
      // younger = Z(t-1)4 + A/S/Z(t)16 = 20). GEMM1 can start; Z-gather
      // and A-state latency hide under the 32-MFMA burst. ----
      asm volatile("s_waitcnt vmcnt(20)" ::: "memory");
      SB();
    } else {
      asm volatile("s_waitcnt vmcnt(0)" ::: "memory");   // last iter: drain
      SB();
    }

    // ---- compute(t) part 1: GEMM1 (LDS hE x reg W1), 32 MFMA ----
    f32x4 acc1[8];
    #pragma unroll
    for (int ct = 0; ct < 8; ++ct) acc1[ct] = (f32x4){0,0,0,0};

    s16x8 afr[4];
    const char* cbuf = mybuf + (t&1)*8192;
    const int sw = (l15 & 7) << 4;
    const int rowb = l15 * 512;
    #pragma unroll
    for (int ks = 0; ks < 4; ++ks){
      const int c0 = ks*128 + lg*32;
      float4 ex = *(const float4*)(cbuf + rowb + (c0 ^ sw));
      float4 ey = *(const float4*)(cbuf + rowb + ((c0 + 16) ^ sw));
      u32x4 pk;
      pk[0] = cvt_pk_bf16(ex.x, ex.y); pk[1] = cvt_pk_bf16(ex.z, ex.w);
      pk[2] = cvt_pk_bf16(ey.x, ey.y); pk[3] = cvt_pk_bf16(ey.z, ey.w);
      afr[ks] = __builtin_bit_cast(s16x8, pk);
      #pragma unroll
      for (int ct = 0; ct < 8; ++ct)
        acc1[ct] = mfma16(afr[ks], wf[ks][ct], acc1[ct]);
    }

    // ---- SPLIT WAIT 2: Z(t-1)=zbC + A(t-1)=uh/mask complete
    // (younger = A/S/Z(t) = 16). ----
    if (t < 7){
      asm volatile("s_waitcnt vmcnt(16)" ::: "memory");
      SB();
    }

    // ---- compute(t) part 2: Z inject (8 MFMA) + U' + mask + gelu ----
    #pragma unroll
    for (int ks = 0; ks < 4; ++ks)
      #pragma unroll
      for (int c2 = 0; c2 < 2; ++c2)
        acc1[ks*2 + c2] = mfma16(zbC[ks], ifr[c2], acc1[ks*2 + c2]);

    float uv[8];
    #pragma unroll
    for (int ct = 0; ct < 4; ++ct){ uv[ct] = bf2f(uhC[0][2*ct]); uv[4+ct] = bf2f(uhC[1][2*ct]); }
    float mi[4];
    #pragma unroll
    for (int i = 0; i < 4; ++i) mi[i] = __shfl(maskC, lg*4 + i, 64);
    #pragma unroll
    for (int ct = 0; ct < 8; ++ct)
      #pragma unroll
      for (int i = 0; i < 4; ++i)
        vacc[ct] += fast_gelu(uv[ct] + mi[i]*acc1[ct][i]);

    // ---- odd iter: node complete -> reduce 32 edges, park v in LDS ----
    if (t & 1){
      short* vl = vpark + (t >> 1)*128;              // compile-time offset
      #pragma unroll
      for (int ct = 0; ct < 8; ++ct){
        float s = vacc[ct];
        s += __shfl_xor(s, 16, 64);
        s += __shfl_xor(s, 32, 64);
        vacc[ct] = 0.f;
        if (ct == lg*2 || ct == lg*2 + 1)
          vl[ct*16 + l15] = f2bf(s);
      }
    }

    // rotate
    if (t < 7){
      maskC = maskN; uhC[0] = uhN0; uhC[1] = uhN1; eZ = eN;
      zbC[0] = zbN0; zbC[1] = zbN1; zbC[2] = zbN2; zbC[3] = zbN3;
    }
  }

  // ---- post-loop epilogue: GEMM2 + LayerNorm + store, per node ----
  asm volatile("s_waitcnt lgkmcnt(0)" ::: "memory");  // v-park visible (r2/r6)
  SB();

  float w2b8[8], lngv[2], lnbv[2];
  #pragma unroll
  for (int ct = 0; ct < 8; ++ct) w2b8[ct] = W2b[ct*16 + l15];
  #pragma unroll
  for (int q = 0; q < 2; ++q){
    const int c = (lg*2 + q)*16 + l15;
    lngv[q] = lng[c]; lnbv[q] = lnb[c];
  }

  #pragma unroll
  for (int nd = 0; nd < 4; ++nd){
    const short* vl = vpark + nd*128;
    f32x4 acc2[8];
    #pragma unroll
    for (int ct = 0; ct < 8; ++ct) acc2[ct] = (f32x4){0,0,0,0};
    #pragma unroll
    for (int ks2 = 0; ks2 < 4; ++ks2){
      s16x8 av = *(const s16x8*)(vl + ks2*32 + lg*8);
      const short* wb2 = W2f + ks2*4096 + lane*8;    // global, L1/L2-hot
      #pragma unroll
      for (int ct = 0; ct < 8; ++ct){
        s16x8 bf = *(const s16x8*)(wb2 + ct*512);
        acc2[ct] = mfma16(av, bf, acc2[ct]);
      }
    }

    s16x8 uh0 = *(const s16x8*)((const short*)UHb + (long)(n0+nd)*256 + l15*16);
    s16x8 uh1 = *(const s16x8*)((const short*)UHb + (long)(n0+nd)*256 + l15*16 + 8);
    float hv[8];
    #pragma unroll
    for (int ct = 0; ct < 4; ++ct){ hv[ct] = bf2f(uh0[2*ct+1]); hv[4+ct] = bf2f(uh1[2*ct+1]); }

    float res[8], vs = 0.f, vq = 0.f;
    #pragma unroll
    for (int ct = 0; ct < 8; ++ct){
      float dh  = (acc2[ct][0] + 32.0f * w2b8[ct]) * (1.0f/30.0f);
      float val = hv[ct] + dh;
      res[ct] = val;
      vs += val; vq += val*val;
    }
    vs += __shfl_xor(vs, 1, 64);  vs += __shfl_xor(vs, 2, 64);
    vs += __shfl_xor(vs, 4, 64);  vs += __shfl_xor(vs, 8, 64);
    vq += __shfl_xor(vq, 1, 64);  vq += __shfl_xor(vq, 2, 64);
    vq += __shfl_xor(vq, 4, 64);  vq += __shfl_xor(vq, 8, 64);
    const float mu  = vs * (1.0f/128.0f);
    const float var = vq * (1.0f/128.0f) - mu*mu;
    const float rs  = rsqrtf(var + 1e-5f);

    const long nodeoff = (long)(n0 + nd) * HDIM;
    #pragma unroll
    for (int q = 0; q < 2; ++q){
      const int ct = lg*2 + q;
      out[nodeoff + ct*16 + l15] = (res[ct] - mu) * rs * lngv[q] + lnbv[q];
    }
  }
}

extern "C" void kernel_launch(void* const* d_in, const int* in_sizes, int n_in,
                              void* d_out, int out_size, void* d_ws, size_t ws_size,
                              hipStream_t stream) {
  const float* hS  = (const float*)d_in[0];
  const float* hV  = (const float*)d_in[1];
  const float* hE  = (const float*)d_in[2];
  const int*   Ei  = (const int*)d_in[3];
  const float* mk  = (const float*)d_in[4];
  const float* W1w = (const float*)d_in[5];
  const float* W1b = (const float*)d_in[6];
  const float* W2w = (const float*)d_in[7];
  const float* W2b = (const float*)d_in[8];
  const float* lng = (const float*)d_in[9];
  const float* lnb = (const float*)d_in[10];

  short* W1f = (short*)d_ws;                           // 128 KB @0
  short* W2f = W1f + 65536;                            // 32 KB @131072
  unsigned* flag = (unsigned*)((char*)d_ws + 163840);
  short* Zb = (short*)((char*)d_ws + 164096);          // 2 MB
  unsigned* UHb = (unsigned*)((char*)d_ws + 2261248);  // 4 MB
  // ~6.5 MB used; ws is >=512 MB (r14 fillBuffer evidence)

  prep1<<<321, 256, 0, stream>>>(W1w, W2w, W1f, W2f, flag);
  prep2<<<640, 256, 0, stream>>>(hS, hV, W1b, W1f, Zb, UHb, (const unsigned*)Ei, flag);
  fusedF<<<512, 256, 0, stream>>>(hE, Ei, mk, W1f, W2f, Zb, UHb, flag,
                                  W2b, lng, lnb, (float*)d_out);
}

// Round 20
// 88.298 us; speedup vs baseline: 1.0662x; 1.0026x over previous
//
#include <hip/hip_runtime.h>
#include <math.h>

typedef float f32x4 __attribute__((ext_vector_type(4)));
typedef short s16x8 __attribute__((ext_vector_type(8)));
typedef unsigned u32x4 __attribute__((ext_vector_type(4)));

#define N_NODES 2048
#define KEDGE 32
#define HDIM 128
#define SB() __builtin_amdgcn_sched_barrier(0)

__device__ __forceinline__ short f2bf(float f){
  unsigned u = __builtin_bit_cast(unsigned, f);
  u += 0x7fffu + ((u >> 16) & 1u);
  return (short)(u >> 16);
}
__device__ __forceinline__ float bf2f(short s){
  unsigned u = ((unsigned)(unsigned short)s) << 16;
  return __builtin_bit_cast(float, u);
}
__device__ __forceinline__ unsigned cvt_pk_bf16(float a, float b){
  unsigned r;
  asm("v_cvt_pk_bf16_f32 %0, %1, %2" : "=v"(r) : "v"(a), "v"(b));
  return r;
}
// tanh-form GELU via exp2+rcp: max abs error vs exact ~5e-4
__device__ __forceinline__ float fast_gelu(float x){
  float t = x * (-2.3022078f - 0.1029527f * x * x);
  float e = __builtin_amdgcn_exp2f(t);
  return x * __builtin_amdgcn_rcpf(1.0f + e);
}
__device__ __forceinline__ void gld16(const void* g, void* l){
  __builtin_amdgcn_global_load_lds(
      (const __attribute__((address_space(1))) void*)g,
      (__attribute__((address_space(3))) void*)l, 16, 0, 0);
}
__device__ __forceinline__ f32x4 mfma16(s16x8 a, s16x8 b, f32x4 c){
  return __builtin_amdgcn_mfma_f32_16x16x32_bf16(a, b, c, 0, 0, 0);
}

// ---- prep1: pack W1/W2 fp32 -> bf16 MFMA B-frag order; init idx flag ----
// elem((ks,ct,lane,j)) = W[ks*32 + (lane>>4)*8 + j][ct*16 + (lane&15)]
__global__ void prep1(const float* __restrict__ W1, const float* __restrict__ W2,
                      short* __restrict__ W1f, short* __restrict__ W2f,
                      unsigned* __restrict__ flag){
  if (blockIdx.x == 320){
    if (threadIdx.x == 0) *flag = 0u;
    return;
  }
  int t = blockIdx.x * 256 + threadIdx.x;
  if (t < 65536){
    int ks = t >> 12, r = t & 4095;
    int ct = r >> 9;  r &= 511;
    int lane = r >> 3, j = r & 7;
    int k = ks*32 + (lane>>4)*8 + j;
    int n = ct*16 + (lane&15);
    W1f[t] = f2bf(W1[k*128 + n]);
  } else if (t < 81920){
    int t2 = t - 65536;
    int ks = t2 >> 12, r = t2 & 4095;
    int ct = r >> 9;  r &= 511;
    int lane = r >> 3, j = r & 7;
    int k = ks*32 + (lane>>4)*8 + j;
    int n = ct*16 + (lane&15);
    W2f[t2] = f2bf(W2[k*128 + n]);
  }
}

// ---- prep2: Zb (bf16 rows) + UHb ({U',hV} bf16 pairs) + E_idx detect ----
//   Zb[m][:]              = bf16( hS(m)@W1c + hV(m)@W1d )
//   UHb[m][l15*8 + ct]    = u32( bf16(U'[ct*16+l15]) | bf16(hV[ct*16+l15])<<16 )
__global__ __launch_bounds__(256)
void prep2(const float* __restrict__ hS, const float* __restrict__ hV,
           const float* __restrict__ b1, const short* __restrict__ W1f,
           short* __restrict__ Zb, unsigned* __restrict__ UHb,
           const unsigned* __restrict__ Ei_u, unsigned* __restrict__ flag){
  if (blockIdx.x >= 128){
    int t = ((int)blockIdx.x - 128)*256 + threadIdx.x;   // t < 131072
    unsigned v = Ei_u[2*t + 1];
    unsigned long long m = __ballot(v != 0u);
    if ((threadIdx.x & 63) == 0 && m) atomicOr(flag, 1u);
    return;
  }
  const int tid = threadIdx.x;
  const int w = tid >> 6, lane = tid & 63, l15 = lane & 15, lg = lane >> 4;
  const int nb = ((int)blockIdx.x*4 + w)*16;

  f32x4 accz[8], accu[8];
  #pragma unroll
  for (int ct = 0; ct < 8; ++ct){ accz[ct] = (f32x4){0,0,0,0}; accu[ct] = (f32x4){0,0,0,0}; }

  #pragma unroll
  for (int ks = 0; ks < 4; ++ks){
    const float* p = hS + (long)(nb + l15)*128 + ks*32 + lg*8;
    float4 x = *(const float4*)p, y = *(const float4*)(p + 4);
    u32x4 pk;
    pk[0] = cvt_pk_bf16(x.x, x.y); pk[1] = cvt_pk_bf16(x.z, x.w);
    pk[2] = cvt_pk_bf16(y.x, y.y); pk[3] = cvt_pk_bf16(y.z, y.w);
    s16x8 a = __builtin_bit_cast(s16x8, pk);
    #pragma unroll
    for (int ct = 0; ct < 8; ++ct){
      s16x8 bf = *(const s16x8*)(W1f + (8+ks)*4096 + ct*512 + lane*8);
      accz[ct] = mfma16(a, bf, accz[ct]);
    }
  }
  #pragma unroll
  for (int ks = 0; ks < 4; ++ks){
    const float* p = hV + (long)(nb + l15)*128 + ks*32 + lg*8;
    float4 x = *(const float4*)p, y = *(const float4*)(p + 4);
    u32x4 pk;
    pk[0] = cvt_pk_bf16(x.x, x.y); pk[1] = cvt_pk_bf16(x.z, x.w);
    pk[2] = cvt_pk_bf16(y.x, y.y); pk[3] = cvt_pk_bf16(y.z, y.w);
    s16x8 a = __builtin_bit_cast(s16x8, pk);
    #pragma unroll
    for (int ct = 0; ct < 8; ++ct){
      s16x8 bfd = *(const s16x8*)(W1f + (12+ks)*4096 + ct*512 + lane*8);
      accz[ct] = mfma16(a, bfd, accz[ct]);
      s16x8 bfa = *(const s16x8*)(W1f + (0+ks)*4096 + ct*512 + lane*8);
      accu[ct] = mfma16(a, bfa, accu[ct]);
    }
  }

  float b1v[8];
  #pragma unroll
  for (int ct = 0; ct < 8; ++ct) b1v[ct] = b1[ct*16 + l15];

  #pragma unroll
  for (int ct = 0; ct < 8; ++ct)
    #pragma unroll
    for (int i = 0; i < 4; ++i){
      const long row = nb + lg*4 + i;
      Zb[row*128 + ct*16 + l15] = f2bf(accz[ct][i]);
      unsigned u16 = (unsigned)(unsigned short)f2bf(accu[ct][i] + b1v[ct]);
      unsigned h16 = (unsigned)(unsigned short)f2bf(hV[row*128 + ct*16 + l15]);
      UHb[row*128 + l15*8 + ct] = u16 | (h16 << 16);
    }
}

// ---- fused: r17 verified optimum + T5 setprio around the compute phase.
// 256 thr (4 waves), grid 512, __launch_bounds__(256,1) (only no-spill
// spelling >128 VGPR; 176 VGPR). LDS 68KB -> 2 blocks/CU -> 2 waves/SIMD.
// Waves are barrier-free/independent -> the T5-positive regime (m191):
// setprio(1) biases issue toward the wave whose data is ready, against
// its partner stalled at a vmcnt.
__global__ __launch_bounds__(256, 1)
void fusedF(const float* __restrict__ hE, const int* __restrict__ Eidx,
            const float* __restrict__ mask, const short* __restrict__ W1f,
            const short* __restrict__ W2f, const short* __restrict__ Zb,
            const unsigned* __restrict__ UHb, const unsigned* __restrict__ idx_flag,
            const float* __restrict__ W2b, const float* __restrict__ lng,
            const float* __restrict__ lnb, float* __restrict__ out)
{
  // [0,65536): 4 waves x (2 x 8KB hE dbuf); [65536,69632): v-park (4 x 1KB)
  __shared__ __align__(16) char smem[69632];

  const int tid  = threadIdx.x;
  const int w    = tid >> 6;
  const int lane = tid & 63;
  const int l15  = lane & 15;
  const int lg   = lane >> 4;

  const int bid  = (int)blockIdx.x;
  const int bswz = (bid & 7)*64 + (bid >> 3);        // XCD swizzle (512%8==0)
  const int n0 = (bswz * 4 + w) * 4;                 // 4 nodes/wave: 8192 total
  const long zrow0 = (long)(n0 >> 11) * N_NODES;     // batch base (r8 lesson)
  char* mybuf  = smem + w*16384;
  short* vpark = (short*)(smem + 65536 + w*1024);    // 4 nodes x 128 bf16

  // staging source swizzle (m173, r12/r14-verified):
  // row = 2q+rr; LDS[row*512+col] = hErow[col ^ ((row&7)<<4)]
  const int rr = lane >> 5;
  const unsigned t0 = (unsigned)((rr << 9) | (((lane & 31) << 4) ^ (rr << 4)));

  // ---- W1b B-frags into registers (128 VGPR) ----
  s16x8 wf[4][8];
  #pragma unroll
  for (int ks = 0; ks < 4; ++ks)
    #pragma unroll
    for (int ct = 0; ct < 8; ++ct)
      wf[ks][ct] = *(const s16x8*)(W1f + (4+ks)*4096 + ct*512 + lane*8);
  SB();

  // identity B-frags for Z injection (exact in bf16)
  s16x8 ifr[2];
  #pragma unroll
  for (int c2 = 0; c2 < 2; ++c2){
    const int active = ((lg >> 1) == c2);
    const int j = l15 - 8*(lg & 1);
    s16x8 f;
    #pragma unroll
    for (int e = 0; e < 8; ++e)
      f[e] = (active && j == e) ? (short)0x3F80 : (short)0;
    ifr[c2] = f;
  }

  const int is64 = (*idx_flag == 0u) ? 1 : 0;

  // ---- prologue: A(0), S(0)=stage(it0), Z(0)=zb(it0) ----
  int e0, eZ;
  {
    const int ea = n0*32 + l15;                      // it0: node n0, half 0
    const int eb = n0*32 + 16 + l15;                 // it1: node n0, half 1
    e0 = Eidx[ea << is64];
    eZ = Eidx[eb << is64];
  }
  float maskC = mask[n0*32 + l15];
  s16x8 uhC[2];
  uhC[0] = *(const s16x8*)((const short*)UHb + (long)n0*256 + l15*16);
  uhC[1] = *(const s16x8*)((const short*)UHb + (long)n0*256 + l15*16 + 8);
  SB();
  #pragma unroll
  for (int q = 0; q < 8; ++q){
    const unsigned off = (unsigned)(q*1024) | (t0 ^ (unsigned)((2*q & 6) << 4));
    gld16((const char*)hE + (size_t)n0*16384 + off, mybuf + q*1024);
  }
  SB();
  s16x8 zbC[4];
  #pragma unroll
  for (int ks = 0; ks < 4; ++ks)
    zbC[ks] = *(const s16x8*)(Zb + (zrow0 + e0)*128 + ks*32 + lg*8);
  SB();
  asm volatile("s_waitcnt vmcnt(0)" ::: "memory");   // cold start (once)
  SB();

  float vacc[8];
  #pragma unroll
  for (int ct = 0; ct < 8; ++ct) vacc[ct] = 0.f;

  #pragma unroll
  for (int t = 0; t < 8; ++t){
    const int tn = t + 1;
    float maskN = 0.f; s16x8 uhN0{}, uhN1{}; int eN = 0;
    s16x8 zbN0{}, zbN1{}, zbN2{}, zbN3{};
    if (t < 7){
      const int nn_n = n0 + (tn >> 1);
      // ---- A: state for t+1 (mask, uh) and eidx for t+2 : 4 VMEM ----
      SB();
      maskN = mask[nn_n*32 + (tn&1)*16 + l15];
      uhN0 = *(const s16x8*)((const short*)UHb + (long)nn_n*256 + l15*16);
      uhN1 = *(const s16x8*)((const short*)UHb + (long)nn_n*256 + l15*16 + 8);
      {
        const int t2 = t + 2;
        const int nz = (t2 <= 7) ? (n0 + (t2>>1)) : n0;   // compile-time select
        const int hz = (t2 <= 7) ? (t2&1) : 0;
        eN = Eidx[(nz*32 + hz*16 + l15) << is64];
      }
      SB();
      // ---- S: stage(t+1) -> slot (t+1)&1 : exactly 8 gld16 ----
      {
        const size_t eb = (size_t)nn_n*16384 + (size_t)(tn&1)*8192;
        char* sbuf = mybuf + (tn&1)*8192;
        #pragma unroll
        for (int q = 0; q < 8; ++q){
          const unsigned off = (unsigned)(q*1024) | (t0 ^ (unsigned)((2*q & 6) << 4));
          gld16((const char*)hE + eb + off, sbuf + q*1024);
        }
      }
      SB();
      // ---- Z: zb(t+1) : 4 gathered b128 (Zb is L2-resident) ----
      zbN0 = *(const s16x8*)(Zb + (zrow0 + eZ)*128 + 0*32 + lg*8);
      zbN1 = *(const s16x8*)(Zb + (zrow0 + eZ)*128 + 1*32 + lg*8);
      zbN2 = *(const s16x8*)(Zb + (zrow0 + eZ)*128 + 2*32 + lg*8);
      zbN3 = *(const s16x8*)(Zb + (zrow0 + eZ)*128 + 3*32 + lg*8);
      SB();
      // ---- SPLIT WAIT 1: S(t) complete (younger = Z(t-1)4 + A/S/Z(t)16
      // = 20). GEMM1 can start; Z/A latency hides under the MFMA burst. ----
      asm volatile("s_waitcnt vmcnt(20)" ::: "memory");
      SB();
    } else {
      asm volatile("s_waitcnt vmcnt(0)" ::: "memory");   // last iter: drain
      SB();
    }

    // ---- compute(t): high-priority region (T5) ----
    __builtin_amdgcn_s_setprio(1);

    // part 1: GEMM1 (LDS hE x reg W1), 32 MFMA
    f32x4 acc1[8];
    #pragma unroll
    for (int ct = 0; ct < 8; ++ct) acc1[ct] = (f32x4){0,0,0,0};

    s16x8 afr[4];
    const char* cbuf = mybuf + (t&1)*8192;
    const int sw = (l15 & 7) << 4;
    const int rowb = l15 * 512;
    #pragma unroll
    for (int ks = 0; ks < 4; ++ks){
      const int c0 = ks*128 + lg*32;
      float4 ex = *(const float4*)(cbuf + rowb + (c0 ^ sw));
      float4 ey = *(const float4*)(cbuf + rowb + ((c0 + 16) ^ sw));
      u32x4 pk;
      pk[0] = cvt_pk_bf16(ex.x, ex.y); pk[1] = cvt_pk_bf16(ex.z, ex.w);
      pk[2] = cvt_pk_bf16(ey.x, ey.y); pk[3] = cvt_pk_bf16(ey.z, ey.w);
      afr[ks] = __builtin_bit_cast(s16x8, pk);
      #pragma unroll
      for (int ct = 0; ct < 8; ++ct)
        acc1[ct] = mfma16(afr[ks], wf[ks][ct], acc1[ct]);
    }

    // SPLIT WAIT 2: Z(t-1)=zbC + A(t-1)=uh/mask complete (younger = 16)
    if (t < 7){
      asm volatile("s_waitcnt vmcnt(16)" ::: "memory");
      SB();
    }

    // part 2: Z inject (8 MFMA) + U' + mask + gelu
    #pragma unroll
    for (int ks = 0; ks < 4; ++ks)
      #pragma unroll
      for (int c2 = 0; c2 < 2; ++c2)
        acc1[ks*2 + c2] = mfma16(zbC[ks], ifr[c2], acc1[ks*2 + c2]);

    float uv[8];
    #pragma unroll
    for (int ct = 0; ct < 4; ++ct){ uv[ct] = bf2f(uhC[0][2*ct]); uv[4+ct] = bf2f(uhC[1][2*ct]); }
    float mi[4];
    #pragma unroll
    for (int i = 0; i < 4; ++i) mi[i] = __shfl(maskC, lg*4 + i, 64);
    #pragma unroll
    for (int ct = 0; ct < 8; ++ct)
      #pragma unroll
      for (int i = 0; i < 4; ++i)
        vacc[ct] += fast_gelu(uv[ct] + mi[i]*acc1[ct][i]);

    __builtin_amdgcn_s_setprio(0);   // end high-priority compute region

    // ---- odd iter: node complete -> reduce 32 edges, park v in LDS ----
    if (t & 1){
      short* vl = vpark + (t >> 1)*128;              // compile-time offset
      #pragma unroll
      for (int ct = 0; ct < 8; ++ct){
        float s = vacc[ct];
        s += __shfl_xor(s, 16, 64);
        s += __shfl_xor(s, 32, 64);
        vacc[ct] = 0.f;
        if (ct == lg*2 || ct == lg*2 + 1)
          vl[ct*16 + l15] = f2bf(s);
      }
    }

    // rotate
    if (t < 7){
      maskC = maskN; uhC[0] = uhN0; uhC[1] = uhN1; eZ = eN;
      zbC[0] = zbN0; zbC[1] = zbN1; zbC[2] = zbN2; zbC[3] = zbN3;
    }
  }

  // ---- post-loop epilogue: GEMM2 + LayerNorm + store, per node ----
  asm volatile("s_waitcnt lgkmcnt(0)" ::: "memory");  // v-park visible (r2/r6)
  SB();

  float w2b8[8], lngv[2], lnbv[2];
  #pragma unroll
  for (int ct = 0; ct < 8; ++ct) w2b8[ct] = W2b[ct*16 + l15];
  #pragma unroll
  for (int q = 0; q < 2; ++q){
    const int c = (lg*2 + q)*16 + l15;
    lngv[q] = lng[c]; lnbv[q] = lnb[c];
  }

  #pragma unroll
  for (int nd = 0; nd < 4; ++nd){
    const short* vl = vpark + nd*128;
    f32x4 acc2[8];
    #pragma unroll
    for (int ct = 0; ct < 8; ++ct) acc2[ct] = (f32x4){0,0,0,0};
    #pragma unroll
    for (int ks2 = 0; ks2 < 4; ++ks2){
      s16x8 av = *(const s16x8*)(vl + ks2*32 + lg*8);
      const short* wb2 = W2f + ks2*4096 + lane*8;    // global, L1/L2-hot
      #pragma unroll
      for (int ct = 0; ct < 8; ++ct){
        s16x8 bf = *(const s16x8*)(wb2 + ct*512);
        acc2[ct] = mfma16(av, bf, acc2[ct]);
      }
    }

    s16x8 uh0 = *(const s16x8*)((const short*)UHb + (long)(n0+nd)*256 + l15*16);
    s16x8 uh1 = *(const s16x8*)((const short*)UHb + (long)(n0+nd)*256 + l15*16 + 8);
    float hv[8];
    #pragma unroll
    for (int ct = 0; ct < 4; ++ct){ hv[ct] = bf2f(uh0[2*ct+1]); hv[4+ct] = bf2f(uh1[2*ct+1]); }

    float res[8], vs = 0.f, vq = 0.f;
    #pragma unroll
    for (int ct = 0; ct < 8; ++ct){
      float dh  = (acc2[ct][0] + 32.0f * w2b8[ct]) * (1.0f/30.0f);
      float val = hv[ct] + dh;
      res[ct] = val;
      vs += val; vq += val*val;
    }
    vs += __shfl_xor(vs, 1, 64);  vs += __shfl_xor(vs, 2, 64);
    vs += __shfl_xor(vs, 4, 64);  vs += __shfl_xor(vs, 8, 64);
    vq += __shfl_xor(vq, 1, 64);  vq += __shfl_xor(vq, 2, 64);
    vq += __shfl_xor(vq, 4, 64);  vq += __shfl_xor(vq, 8, 64);
    const float mu  = vs * (1.0f/128.0f);
    const float var = vq * (1.0f/128.0f) - mu*mu;
    const float rs  = rsqrtf(var + 1e-5f);

    const long nodeoff = (long)(n0 + nd) * HDIM;
    #pragma unroll
    for (int q = 0; q < 2; ++q){
      const int ct = lg*2 + q;
      out[nodeoff + ct*16 + l15] = (res[ct] - mu) * rs * lngv[q] + lnbv[q];
    }
  }
}

extern "C" void kernel_launch(void* const* d_in, const int* in_sizes, int n_in,
                              void* d_out, int out_size, void* d_ws, size_t ws_size,
                              hipStream_t stream) {
  const float* hS  = (const float*)d_in[0];
  const float* hV  = (const float*)d_in[1];
  const float* hE  = (const float*)d_in[2];
  const int*   Ei  = (const int*)d_in[3];
  const float* mk  = (const float*)d_in[4];
  const float* W1w = (const float*)d_in[5];
  const float* W1b = (const float*)d_in[6];
  const float* W2w = (const float*)d_in[7];
  const float* W2b = (const float*)d_in[8];
  const float* lng = (const float*)d_in[9];
  const float* lnb = (const float*)d_in[10];

  short* W1f = (short*)d_ws;                           // 128 KB @0
  short* W2f = W1f + 65536;                            // 32 KB @131072
  unsigned* flag = (unsigned*)((char*)d_ws + 163840);
  short* Zb = (short*)((char*)d_ws + 164096);          // 2 MB
  unsigned* UHb = (unsigned*)((char*)d_ws + 2261248);  // 4 MB
  // ~6.5 MB used; ws is >=512 MB (r14 fillBuffer evidence)

  prep1<<<321, 256, 0, stream>>>(W1w, W2w, W1f, W2f, flag);
  prep2<<<640, 256, 0, stream>>>(hS, hV, W1b, W1f, Zb, UHb, (const unsigned*)Ei, flag);
  fusedF<<<512, 256, 0, stream>>>(hE, Ei, mk, W1f, W2f, Zb, UHb, flag,
                                  W2b, lng, lnb, (float*)d_out);
}

// Round 21
// 81.362 us; speedup vs baseline: 1.1572x; 1.0853x over previous
//
#include <hip/hip_runtime.h>
#include <math.h>

typedef float f32x4 __attribute__((ext_vector_type(4)));
typedef short s16x8 __attribute__((ext_vector_type(8)));
typedef unsigned u32x4 __attribute__((ext_vector_type(4)));

#define N_NODES 2048
#define KEDGE 32
#define HDIM 128
#define SB() __builtin_amdgcn_sched_barrier(0)

__device__ __forceinline__ short f2bf(float f){
  unsigned u = __builtin_bit_cast(unsigned, f);
  u += 0x7fffu + ((u >> 16) & 1u);
  return (short)(u >> 16);
}
__device__ __forceinline__ float bf2f(short s){
  unsigned u = ((unsigned)(unsigned short)s) << 16;
  return __builtin_bit_cast(float, u);
}
__device__ __forceinline__ unsigned cvt_pk_bf16(float a, float b){
  unsigned r;
  asm("v_cvt_pk_bf16_f32 %0, %1, %2" : "=v"(r) : "v"(a), "v"(b));
  return r;
}
// tanh-form GELU via exp2+rcp: max abs error vs exact ~5e-4
__device__ __forceinline__ float fast_gelu(float x){
  float t = x * (-2.3022078f - 0.1029527f * x * x);
  float e = __builtin_amdgcn_exp2f(t);
  return x * __builtin_amdgcn_rcpf(1.0f + e);
}
__device__ __forceinline__ void gld16(const void* g, void* l){
  __builtin_amdgcn_global_load_lds(
      (const __attribute__((address_space(1))) void*)g,
      (__attribute__((address_space(3))) void*)l, 16, 0, 0);
}
__device__ __forceinline__ f32x4 mfma16(s16x8 a, s16x8 b, f32x4 c){
  return __builtin_amdgcn_mfma_f32_16x16x32_bf16(a, b, c, 0, 0, 0);
}

// ---- prep1: pack W1/W2 fp32 -> bf16 MFMA B-frag order; init idx flag ----
// elem((ks,ct,lane,j)) = W[ks*32 + (lane>>4)*8 + j][ct*16 + (lane&15)]
__global__ void prep1(const float* __restrict__ W1, const float* __restrict__ W2,
                      short* __restrict__ W1f, short* __restrict__ W2f,
                      unsigned* __restrict__ flag){
  if (blockIdx.x == 320){
    if (threadIdx.x == 0) *flag = 0u;
    return;
  }
  int t = blockIdx.x * 256 + threadIdx.x;
  if (t < 65536){
    int ks = t >> 12, r = t & 4095;
    int ct = r >> 9;  r &= 511;
    int lane = r >> 3, j = r & 7;
    int k = ks*32 + (lane>>4)*8 + j;
    int n = ct*16 + (lane&15);
    W1f[t] = f2bf(W1[k*128 + n]);
  } else if (t < 81920){
    int t2 = t - 65536;
    int ks = t2 >> 12, r = t2 & 4095;
    int ct = r >> 9;  r &= 511;
    int lane = r >> 3, j = r & 7;
    int k = ks*32 + (lane>>4)*8 + j;
    int n = ct*16 + (lane&15);
    W2f[t2] = f2bf(W2[k*128 + n]);
  }
}

// ---- prep2: Zb (bf16 rows) + UHb ({U',hV} bf16 pairs) + E_idx detect ----
//   Zb[m][:]              = bf16( hS(m)@W1c + hV(m)@W1d )
//   UHb[m][l15*8 + ct]    = u32( bf16(U'[ct*16+l15]) | bf16(hV[ct*16+l15])<<16 )
__global__ __launch_bounds__(256)
void prep2(const float* __restrict__ hS, const float* __restrict__ hV,
           const float* __restrict__ b1, const short* __restrict__ W1f,
           short* __restrict__ Zb, unsigned* __restrict__ UHb,
           const unsigned* __restrict__ Ei_u, unsigned* __restrict__ flag){
  if (blockIdx.x >= 128){
    int t = ((int)blockIdx.x - 128)*256 + threadIdx.x;   // t < 131072
    unsigned v = Ei_u[2*t + 1];
    unsigned long long m = __ballot(v != 0u);
    if ((threadIdx.x & 63) == 0 && m) atomicOr(flag, 1u);
    return;
  }
  const int tid = threadIdx.x;
  const int w = tid >> 6, lane = tid & 63, l15 = lane & 15, lg = lane >> 4;
  const int nb = ((int)blockIdx.x*4 + w)*16;

  f32x4 accz[8], accu[8];
  #pragma unroll
  for (int ct = 0; ct < 8; ++ct){ accz[ct] = (f32x4){0,0,0,0}; accu[ct] = (f32x4){0,0,0,0}; }

  #pragma unroll
  for (int ks = 0; ks < 4; ++ks){
    const float* p = hS + (long)(nb + l15)*128 + ks*32 + lg*8;
    float4 x = *(const float4*)p, y = *(const float4*)(p + 4);
    u32x4 pk;
    pk[0] = cvt_pk_bf16(x.x, x.y); pk[1] = cvt_pk_bf16(x.z, x.w);
    pk[2] = cvt_pk_bf16(y.x, y.y); pk[3] = cvt_pk_bf16(y.z, y.w);
    s16x8 a = __builtin_bit_cast(s16x8, pk);
    #pragma unroll
    for (int ct = 0; ct < 8; ++ct){
      s16x8 bf = *(const s16x8*)(W1f + (8+ks)*4096 + ct*512 + lane*8);
      accz[ct] = mfma16(a, bf, accz[ct]);
    }
  }
  #pragma unroll
  for (int ks = 0; ks < 4; ++ks){
    const float* p = hV + (long)(nb + l15)*128 + ks*32 + lg*8;
    float4 x = *(const float4*)p, y = *(const float4*)(p + 4);
    u32x4 pk;
    pk[0] = cvt_pk_bf16(x.x, x.y); pk[1] = cvt_pk_bf16(x.z, x.w);
    pk[2] = cvt_pk_bf16(y.x, y.y); pk[3] = cvt_pk_bf16(y.z, y.w);
    s16x8 a = __builtin_bit_cast(s16x8, pk);
    #pragma unroll
    for (int ct = 0; ct < 8; ++ct){
      s16x8 bfd = *(const s16x8*)(W1f + (12+ks)*4096 + ct*512 + lane*8);
      accz[ct] = mfma16(a, bfd, accz[ct]);
      s16x8 bfa = *(const s16x8*)(W1f + (0+ks)*4096 + ct*512 + lane*8);
      accu[ct] = mfma16(a, bfa, accu[ct]);
    }
  }

  float b1v[8];
  #pragma unroll
  for (int ct = 0; ct < 8; ++ct) b1v[ct] = b1[ct*16 + l15];

  #pragma unroll
  for (int ct = 0; ct < 8; ++ct)
    #pragma unroll
    for (int i = 0; i < 4; ++i){
      const long row = nb + lg*4 + i;
      Zb[row*128 + ct*16 + l15] = f2bf(accz[ct][i]);
      unsigned u16 = (unsigned)(unsigned short)f2bf(accu[ct][i] + b1v[ct]);
      unsigned h16 = (unsigned)(unsigned short)f2bf(hV[row*128 + ct*16 + l15]);
      UHb[row*128 + l15*8 + ct] = u16 | (h16 << 16);
    }
}

// ---- fused: 2-wave TEAM structure (ct-split) to reach 3 waves/SIMD.
// Team = 2 waves sharing one half-node tile: each wave stages half
// (4 gld16) and computes 4 of the 8 output ct-columns. Cuts per-wave
// wf 128->64 VGPR, zb 4->2, acc 32->16 (target <=170 VGPR = 3 waves/SIMD
// from the 512-reg/SIMD pool) and LDS/block to 34.8KB (3+ blocks/CU).
// Per-iter block s_barrier gives cross-wave stage visibility; covered by
// cross-block TLP. FIFO (9 ops/iter): wait-1 vmcnt(11) [my stage(t) done]
// -> barrier -> 16 W1-MFMA -> wait-2 vmcnt(9) [zb(t) done] -> inject+gelu.
__global__ __launch_bounds__(256, 1)
void fusedF(const float* __restrict__ hE, const int* __restrict__ Eidx,
            const float* __restrict__ mask, const short* __restrict__ W1f,
            const short* __restrict__ W2f, const short* __restrict__ Zb,
            const unsigned* __restrict__ UHb, const unsigned* __restrict__ idx_flag,
            const float* __restrict__ W2b, const float* __restrict__ lng,
            const float* __restrict__ lnb, float* __restrict__ out)
{
  // [0,32768): 2 teams x (2 x 8KB hE dbuf); [32768,34816): vpark (2 x 1KB)
  __shared__ __align__(16) char smem[34816];

  const int tid  = threadIdx.x;
  const int w    = tid >> 6;
  const int team = w >> 1;
  const int half = w & 1;            // staging half AND ct half
  const int ctb  = half * 4;         // this wave's ct base (0 or 4)
  const int lane = tid & 63;
  const int l15  = lane & 15;
  const int lg   = lane >> 4;

  const int bid  = (int)blockIdx.x;
  const int bswz = (bid & 7)*128 + (bid >> 3);       // XCD swizzle (1024%8==0)
  const int n0 = (bswz*2 + team) * 4;                // 4 nodes/team: 8192 total
  const long zrow0 = (long)(n0 >> 11) * N_NODES;     // batch base (r8 lesson)
  char* mybuf  = smem + team*16384;
  short* vpark = (short*)(smem + 32768 + team*1024); // 4 nodes x 128 bf16

  // staging source swizzle (m173, r12-verified):
  // row = 2qq+rr; LDS[row*512+col] = hErow[col ^ ((row&7)<<4)]
  const int rr = lane >> 5;
  const unsigned t0 = (unsigned)((rr << 9) | (((lane & 31) << 4) ^ (rr << 4)));

  // ---- W1b B-frags for THIS WAVE's 4 ct columns (64 VGPR) ----
  s16x8 wf[4][4];
  #pragma unroll
  for (int ks = 0; ks < 4; ++ks)
    #pragma unroll
    for (int c = 0; c < 4; ++c)
      wf[ks][c] = *(const s16x8*)(W1f + (4+ks)*4096 + (ctb+c)*512 + lane*8);
  SB();

  // identity B-frags for Z injection (exact in bf16; depends only on c2)
  s16x8 ifr[2];
  #pragma unroll
  for (int c2 = 0; c2 < 2; ++c2){
    const int active = ((lg >> 1) == c2);
    const int j = l15 - 8*(lg & 1);
    s16x8 f;
    #pragma unroll
    for (int e = 0; e < 8; ++e)
      f[e] = (active && j == e) ? (short)0x3F80 : (short)0;
    ifr[c2] = f;
  }

  const int is64 = (*idx_flag == 0u) ? 1 : 0;

  // ---- prologue: state(0), stage(0), zb(0) ----
  int e0, eZ;
  {
    const int ea = n0*32 + l15;                      // it0: node n0, half 0
    const int eb = n0*32 + 16 + l15;                 // it1: node n0, half 1
    e0 = Eidx[ea << is64];
    eZ = Eidx[eb << is64];
  }
  float maskC = mask[n0*32 + l15];
  s16x8 uhC = *(const s16x8*)((const short*)UHb + (long)n0*256 + l15*16 + ctb*2);
  SB();
  #pragma unroll
  for (int j = 0; j < 4; ++j){
    const int qq = half*4 + j;
    const unsigned off = (unsigned)(qq*1024) | (t0 ^ (unsigned)((2*qq & 6) << 4));
    gld16((const char*)hE + (size_t)n0*16384 + off, mybuf + qq*1024);
  }
  SB();
  s16x8 zbC[2];
  #pragma unroll
  for (int kk = 0; kk < 2; ++kk)
    zbC[kk] = *(const s16x8*)(Zb + (zrow0 + e0)*128 + (half*2+kk)*32 + lg*8);
  SB();
  asm volatile("s_waitcnt vmcnt(0)" ::: "memory");   // cold start (once)
  SB();
  __builtin_amdgcn_s_barrier();                      // team stage(0) visible

  float vacc[4];
  #pragma unroll
  for (int c = 0; c < 4; ++c) vacc[c] = 0.f;

  #pragma unroll
  for (int t = 0; t < 8; ++t){
    const int tn = t + 1;
    float maskN = 0.f; s16x8 uhN{}; int eN = 0;
    s16x8 zbN0{}, zbN1{};
    if (t < 7){
      const int nn_n = n0 + (tn >> 1);
      // ---- A: state for t+1 (mask, uh) and eidx for t+2 : 3 VMEM ----
      SB();
      maskN = mask[nn_n*32 + (tn&1)*16 + l15];
      uhN = *(const s16x8*)((const short*)UHb + (long)nn_n*256 + l15*16 + ctb*2);
      {
        const int t2 = t + 2;
        const int nz = (t2 <= 7) ? (n0 + (t2>>1)) : n0;   // compile-time select
        const int hz = (t2 <= 7) ? (t2&1) : 0;
        eN = Eidx[(nz*32 + hz*16 + l15) << is64];
      }
      SB();
      // ---- S: my half of stage(t+1) -> slot (t+1)&1 : exactly 4 gld16 ----
      {
        const size_t eb = (size_t)nn_n*16384 + (size_t)(tn&1)*8192;
        char* sbuf = mybuf + (tn&1)*8192;
        #pragma unroll
        for (int j = 0; j < 4; ++j){
          const int qq = half*4 + j;
          const unsigned off = (unsigned)(qq*1024) | (t0 ^ (unsigned)((2*qq & 6) << 4));
          gld16((const char*)hE + eb + off, sbuf + qq*1024);
        }
      }
      SB();
      // ---- Z: zb(t+1), my 2 k-slices (Zb is L2-resident) ----
      zbN0 = *(const s16x8*)(Zb + (zrow0 + eZ)*128 + (half*2+0)*32 + lg*8);
      zbN1 = *(const s16x8*)(Zb + (zrow0 + eZ)*128 + (half*2+1)*32 + lg*8);
      SB();
      // ---- wait-1: my stage(t) complete (younger = Z(t)2 + A3+S4+Z2 = 11) --
      asm volatile("s_waitcnt vmcnt(11)" ::: "memory");
      SB();
    } else {
      asm volatile("s_waitcnt vmcnt(0)" ::: "memory");   // last iter: drain
      SB();
    }
    __builtin_amdgcn_s_barrier();    // team's full tile(t) visible

    // ---- compute(t): high-priority region (T5, r20-verified) ----
    __builtin_amdgcn_s_setprio(1);

    // part 1: GEMM1 on my 4 ct columns (16 MFMA)
    f32x4 acc1[4];
    #pragma unroll
    for (int c = 0; c < 4; ++c) acc1[c] = (f32x4){0,0,0,0};

    const char* cbuf = mybuf + (t&1)*8192;
    const int sw = (l15 & 7) << 4;
    const int rowb = l15 * 512;
    #pragma unroll
    for (int ks = 0; ks < 4; ++ks){
      const int c0 = ks*128 + lg*32;
      float4 ex = *(const float4*)(cbuf + rowb + (c0 ^ sw));
      float4 ey = *(const float4*)(cbuf + rowb + ((c0 + 16) ^ sw));
      u32x4 pk;
      pk[0] = cvt_pk_bf16(ex.x, ex.y); pk[1] = cvt_pk_bf16(ex.z, ex.w);
      pk[2] = cvt_pk_bf16(ey.x, ey.y); pk[3] = cvt_pk_bf16(ey.z, ey.w);
      s16x8 a = __builtin_bit_cast(s16x8, pk);
      #pragma unroll
      for (int c = 0; c < 4; ++c)
        acc1[c] = mfma16(a, wf[ks][c], acc1[c]);
    }

    // wait-2: zb(t)=zbC complete (younger = A3+S4+Z2 = 9)
    if (t < 7){
      asm volatile("s_waitcnt vmcnt(9)" ::: "memory");
      SB();
    }

    // part 2: Z inject (4 MFMA; global ks = half*2+kk -> local ct = kk*2+c2)
    #pragma unroll
    for (int kk = 0; kk < 2; ++kk)
      #pragma unroll
      for (int c2 = 0; c2 < 2; ++c2)
        acc1[kk*2 + c2] = mfma16(zbC[kk], ifr[c2], acc1[kk*2 + c2]);

    float uv[4];
    #pragma unroll
    for (int c = 0; c < 4; ++c) uv[c] = bf2f(uhC[2*c]);
    float mi[4];
    #pragma unroll
    for (int i = 0; i < 4; ++i) mi[i] = __shfl(maskC, lg*4 + i, 64);
    #pragma unroll
    for (int c = 0; c < 4; ++c)
      #pragma unroll
      for (int i = 0; i < 4; ++i)
        vacc[c] += fast_gelu(uv[c] + mi[i]*acc1[c][i]);

    __builtin_amdgcn_s_setprio(0);

    // ---- odd iter: node complete -> reduce my 4 cts, park in LDS ----
    if (t & 1){
      short* vl = vpark + (t >> 1)*128;              // compile-time offset
      #pragma unroll
      for (int c = 0; c < 4; ++c){
        float s = vacc[c];
        s += __shfl_xor(s, 16, 64);
        s += __shfl_xor(s, 32, 64);
        vacc[c] = 0.f;
        if (lg == c)                                 // group lg writes ct=ctb+c
          vl[(ctb + c)*16 + l15] = f2bf(s);
      }
    }

    // rotate
    if (t < 7){
      maskC = maskN; uhC = uhN; eZ = eN;
      zbC[0] = zbN0; zbC[1] = zbN1;
    }
  }

  // ---- epilogue: full-v GEMM2 + LayerNorm; waves split the 4 nodes ----
  asm volatile("s_waitcnt lgkmcnt(0)" ::: "memory");  // my v-park writes done
  SB();
  __builtin_amdgcn_s_barrier();                       // all waves' v visible

  float w2b8[8], lngv[2], lnbv[2];
  #pragma unroll
  for (int ct = 0; ct < 8; ++ct) w2b8[ct] = W2b[ct*16 + l15];
  #pragma unroll
  for (int q = 0; q < 2; ++q){
    const int c = (lg*2 + q)*16 + l15;
    lngv[q] = lng[c]; lnbv[q] = lnb[c];
  }

  #pragma unroll
  for (int j = 0; j < 2; ++j){
    const int nd = half*2 + j;                        // 2 nodes per wave
    const short* vl = vpark + nd*128;
    f32x4 acc2[8];
    #pragma unroll
    for (int ct = 0; ct < 8; ++ct) acc2[ct] = (f32x4){0,0,0,0};
    #pragma unroll
    for (int ks2 = 0; ks2 < 4; ++ks2){
      s16x8 av = *(const s16x8*)(vl + ks2*32 + lg*8);
      const short* wb2 = W2f + ks2*4096 + lane*8;     // global, L1/L2-hot
      #pragma unroll
      for (int ct = 0; ct < 8; ++ct){
        s16x8 bf = *(const s16x8*)(wb2 + ct*512);
        acc2[ct] = mfma16(av, bf, acc2[ct]);
      }
    }

    s16x8 uh0 = *(const s16x8*)((const short*)UHb + (long)(n0+nd)*256 + l15*16);
    s16x8 uh1 = *(const s16x8*)((const short*)UHb + (long)(n0+nd)*256 + l15*16 + 8);
    float hv[8];
    #pragma unroll
    for (int c = 0; c < 4; ++c){ hv[c] = bf2f(uh0[2*c+1]); hv[4+c] = bf2f(uh1[2*c+1]); }

    float res[8], vs = 0.f, vq = 0.f;
    #pragma unroll
    for (int ct = 0; ct < 8; ++ct){
      float dh  = (acc2[ct][0] + 32.0f * w2b8[ct]) * (1.0f/30.0f);
      float val = hv[ct] + dh;
      res[ct] = val;
      vs += val; vq += val*val;
    }
    vs += __shfl_xor(vs, 1, 64);  vs += __shfl_xor(vs, 2, 64);
    vs += __shfl_xor(vs, 4, 64);  vs += __shfl_xor(vs, 8, 64);
    vq += __shfl_xor(vq, 1, 64);  vq += __shfl_xor(vq, 2, 64);
    vq += __shfl_xor(vq, 4, 64);  vq += __shfl_xor(vq, 8, 64);
    const float mu  = vs * (1.0f/128.0f);
    const float var = vq * (1.0f/128.0f) - mu*mu;
    const float rs  = rsqrtf(var + 1e-5f);

    const long nodeoff = (long)(n0 + nd) * HDIM;
    #pragma unroll
    for (int q = 0; q < 2; ++q){
      const int ct = lg*2 + q;
      out[nodeoff + ct*16 + l15] = (res[ct] - mu) * rs * lngv[q] + lnbv[q];
    }
  }
}

extern "C" void kernel_launch(void* const* d_in, const int* in_sizes, int n_in,
                              void* d_out, int out_size, void* d_ws, size_t ws_size,
                              hipStream_t stream) {
  const float* hS  = (const float*)d_in[0];
  const float* hV  = (const float*)d_in[1];
  const float* hE  = (const float*)d_in[2];
  const int*   Ei  = (const int*)d_in[3];
  const float* mk  = (const float*)d_in[4];
  const float* W1w = (const float*)d_in[5];
  const float* W1b = (const float*)d_in[6];
  const float* W2w = (const float*)d_in[7];
  const float* W2b = (const float*)d_in[8];
  const float* lng = (const float*)d_in[9];
  const float* lnb = (const float*)d_in[10];

  short* W1f = (short*)d_ws;                           // 128 KB @0
  short* W2f = W1f + 65536;                            // 32 KB @131072
  unsigned* flag = (unsigned*)((char*)d_ws + 163840);
  short* Zb = (short*)((char*)d_ws + 164096);          // 2 MB
  unsigned* UHb = (unsigned*)((char*)d_ws + 2261248);  // 4 MB
  // ~6.5 MB used; ws is >=512 MB (r14 fillBuffer evidence)

  prep1<<<321, 256, 0, stream>>>(W1w, W2w, W1f, W2f, flag);
  prep2<<<640, 256, 0, stream>>>(hS, hV, W1b, W1f, Zb, UHb, (const unsigned*)Ei, flag);
  fusedF<<<1024, 256, 0, stream>>>(hE, Ei, mk, W1f, W2f, Zb, UHb, flag,
                                   W2b, lng, lnb, (float*)d_out);
}